// Round 1
// baseline (296.001 us; speedup 1.0000x reference)
//
#include <hip/hip_runtime.h>
#include <math.h>

#define KSIZE 7
#define C_CH  256
#define HW    256
#define BATCH 8

#define TH    32            // output rows per block
#define ROWS  (TH + 6)      // input rows staged (halo 3 top + 3 bottom)
#define LDW   264           // 4 zero + 256 + 4 zero padded floats per LDS row

// ---------------------------------------------------------------------------
// Kernel 1: synthesize the 256 x 7 x 7 Gabor filter bank into d_ws.
// One thread per channel; trivial cost (~µs).
// ---------------------------------------------------------------------------
__global__ void gabor_weights_kernel(const float* __restrict__ log_sigma,
                                     const float* __restrict__ log_freq,
                                     const float* __restrict__ theta,
                                     float* __restrict__ gw) {
    int c = threadIdx.x;
    if (c >= C_CH) return;
    float sigma = expf(log_sigma[c]);
    float freq  = expf(log_freq[c]);
    float ct = cosf(theta[c]);
    float st = sinf(theta[c]);
    float inv_sigma = 1.0f / sigma;
    float vals[KSIZE * KSIZE];
    float sum = 0.0f;
    #pragma unroll
    for (int i = 0; i < KSIZE; ++i) {
        #pragma unroll
        for (int j = 0; j < KSIZE; ++j) {
            float dx = (float)(i - 3);   // gx: varies with first (height) axis
            float dy = (float)(j - 3);   // gy: varies with second (width) axis
            float x0 = (dx * ct + dy * st) * inv_sigma;
            float x1 = (-dx * st + dy * ct) * inv_sigma;
            float g  = expf(-0.5f * (x0 * x0 + x1 * x1));
            float v  = g * cosf(6.283185307179586f * freq * x0);
            vals[i * KSIZE + j] = v;
            sum += v;
        }
    }
    float inv = 1.0f / sum;
    #pragma unroll
    for (int k = 0; k < KSIZE * KSIZE; ++k)
        gw[c * (KSIZE * KSIZE) + k] = vals[k] * inv;
}

// ---------------------------------------------------------------------------
// Kernel 2: depthwise 7x7 conv, zero-padded, stride 1.
// Block = 256 threads = (n, c, 32-row tile).  LDS tile: 38 rows x 264 floats
// (4 zero-pad cols each side so all compute reads are 16B-aligned float4).
// Thread layout: wq = tid&63 -> columns [4wq, 4wq+3]; rg = tid>>6 -> rows
// [8rg, 8rg+7].  Each thread: 42 ds_read_b128 -> 1568 FMAs (8x4 outputs).
// Weights are block-uniform -> compiler scalar-loads them (SGPR operands).
// ---------------------------------------------------------------------------
__global__ __launch_bounds__(256, 4)
void gabor_conv_kernel(const float* __restrict__ x,
                       const float* __restrict__ gw,
                       float* __restrict__ out) {
    __shared__ float tile[ROWS][LDW];

    const int tid = threadIdx.x;
    const int ht  = blockIdx.x;   // 0..7   (H/TH row tiles)
    const int c   = blockIdx.y;   // 0..255
    const int n   = blockIdx.z;   // 0..7

    const size_t plane = ((size_t)n * C_CH + c) * (size_t)(HW * HW);
    const float* xp = x + plane;
    float*       op = out + plane;
    const int row0 = ht * TH - 3;   // image row of LDS row 0

    // ---- stage global -> LDS (with zero halo) ----
    const int NF4 = ROWS * (LDW / 4);   // 38 * 66 = 2508 float4 slots
    for (int idx = tid; idx < NF4; idx += 256) {
        int rr = idx / 66;
        int q  = idx - rr * 66;
        float4 v = make_float4(0.f, 0.f, 0.f, 0.f);
        int gr = row0 + rr;
        if (q >= 1 && q <= 64 && gr >= 0 && gr < HW) {
            v = *reinterpret_cast<const float4*>(xp + (size_t)gr * HW + (q - 1) * 4);
        }
        *reinterpret_cast<float4*>(&tile[rr][q * 4]) = v;
    }

    // ---- weights: block-uniform loads (scalar-load friendly) ----
    float w[KSIZE * KSIZE];
    const float* wp = gw + c * (KSIZE * KSIZE);
    #pragma unroll
    for (int k = 0; k < KSIZE * KSIZE; ++k) w[k] = wp[k];

    __syncthreads();

    const int wq   = tid & 63;    // column quad: output cols 4wq..4wq+3
    const int rg   = tid >> 6;    // row group: output tile rows 8rg..8rg+7
    const int ob   = rg * 8;
    const int colp = wq * 4;      // padded col base (16B aligned)

    float acc[8][4];
    #pragma unroll
    for (int o = 0; o < 8; ++o)
        #pragma unroll
        for (int cc = 0; cc < 4; ++cc) acc[o][cc] = 0.f;

    #pragma unroll
    for (int r = 0; r < 14; ++r) {      // LDS rows ob..ob+13
        float4 a = *reinterpret_cast<const float4*>(&tile[ob + r][colp]);
        float4 b = *reinterpret_cast<const float4*>(&tile[ob + r][colp + 4]);
        float4 d = *reinterpret_cast<const float4*>(&tile[ob + r][colp + 8]);
        float f[12] = {a.x, a.y, a.z, a.w, b.x, b.y, b.z, b.w, d.x, d.y, d.z, d.w};
        #pragma unroll
        for (int o = 0; o < 8; ++o) {
            if (o <= r && r <= o + 6) {     // compile-time after unroll
                const int ki = r - o;        // kernel row index 0..6
                #pragma unroll
                for (int cc = 0; cc < 4; ++cc) {
                    #pragma unroll
                    for (int j = 0; j < KSIZE; ++j)
                        acc[o][cc] += f[cc + j + 1] * w[ki * KSIZE + j];
                }
            }
        }
    }

    // ---- write 8 rows x float4, fully coalesced (wave covers a full row) ----
    const int orow0 = ht * TH + ob;
    #pragma unroll
    for (int o = 0; o < 8; ++o) {
        float4 v = make_float4(acc[o][0], acc[o][1], acc[o][2], acc[o][3]);
        *reinterpret_cast<float4*>(op + (size_t)(orow0 + o) * HW + wq * 4) = v;
    }
}

extern "C" void kernel_launch(void* const* d_in, const int* in_sizes, int n_in,
                              void* d_out, int out_size, void* d_ws, size_t ws_size,
                              hipStream_t stream) {
    const float* x  = (const float*)d_in[0];
    const float* ls = (const float*)d_in[1];
    const float* lf = (const float*)d_in[2];
    const float* th = (const float*)d_in[3];
    float* out = (float*)d_out;
    float* gw  = (float*)d_ws;   // 256*49*4 = 50176 bytes of scratch

    gabor_weights_kernel<<<1, 256, 0, stream>>>(ls, lf, th, gw);

    dim3 grid(HW / TH, C_CH, BATCH);
    gabor_conv_kernel<<<grid, 256, 0, stream>>>(x, gw, out);
}

// Round 2
// 282.030 us; speedup vs baseline: 1.0495x; 1.0495x over previous
//
#include <hip/hip_runtime.h>
#include <math.h>

#define KSIZE 7
#define C_CH  256
#define HW    256
#define BATCH 8

#define TH    32            // output rows per tile
#define ROWS  (TH + 6)      // 38 input rows staged (3-row halo each side)
#define LDW   264           // 4 zero + 256 + 4 zero padded floats per LDS row
#define NT    (HW / TH)     // 8 tiles per (n,c) plane

// ---------------------------------------------------------------------------
// Kernel 1: synthesize the 256 x 7 x 7 Gabor filter bank into d_ws.
// ---------------------------------------------------------------------------
__global__ void gabor_weights_kernel(const float* __restrict__ log_sigma,
                                     const float* __restrict__ log_freq,
                                     const float* __restrict__ theta,
                                     float* __restrict__ gw) {
    int c = threadIdx.x;
    if (c >= C_CH) return;
    float sigma = expf(log_sigma[c]);
    float freq  = expf(log_freq[c]);
    float ct = cosf(theta[c]);
    float st = sinf(theta[c]);
    float inv_sigma = 1.0f / sigma;
    float vals[KSIZE * KSIZE];
    float sum = 0.0f;
    #pragma unroll
    for (int i = 0; i < KSIZE; ++i) {
        #pragma unroll
        for (int j = 0; j < KSIZE; ++j) {
            float dx = (float)(i - 3);
            float dy = (float)(j - 3);
            float x0 = (dx * ct + dy * st) * inv_sigma;
            float x1 = (-dx * st + dy * ct) * inv_sigma;
            float g  = expf(-0.5f * (x0 * x0 + x1 * x1));
            float v  = g * cosf(6.283185307179586f * freq * x0);
            vals[i * KSIZE + j] = v;
            sum += v;
        }
    }
    float inv = 1.0f / sum;
    #pragma unroll
    for (int k = 0; k < KSIZE * KSIZE; ++k)
        gw[c * (KSIZE * KSIZE) + k] = vals[k] * inv;
}

// ---------------------------------------------------------------------------
// Kernel 2: depthwise 7x7 conv, persistent block per (n,c) plane, streaming
// 8 row-tiles with double-buffered LDS + async global_load_lds prefetch.
// Per tile: issue next-tile loads -> compute current tile -> store ->
// __syncthreads (drains vmcnt => prefetch complete exactly when needed).
// ---------------------------------------------------------------------------
__device__ __forceinline__ void gload_lds16(const float* g, float* l) {
    __builtin_amdgcn_global_load_lds(
        (const __attribute__((address_space(1))) void*)g,
        (__attribute__((address_space(3))) void*)l,
        16, 0, 0);
}

__global__ __launch_bounds__(256, 2)
void gabor_conv_kernel(const float* __restrict__ x,
                       const float* __restrict__ gw,
                       float* __restrict__ out) {
    __shared__ float tile[2][ROWS][LDW];

    const int tid  = threadIdx.x;
    const int lane = tid & 63;    // column quad: output cols 4*lane..4*lane+3
    const int wv   = tid >> 6;    // wave id: output rows 8*wv..8*wv+7
    const int c    = blockIdx.x;
    const int n    = blockIdx.y;

    const size_t plane = ((size_t)n * C_CH + c) * (size_t)(HW * HW);
    const float* xp = x + plane;
    float*       op = out + plane;

    // ---- zero the pad columns of BOTH buffers once (stages never touch them)
    for (int idx = tid; idx < 2 * ROWS; idx += 256) {
        int b  = idx / ROWS;
        int rr = idx - b * ROWS;
        *reinterpret_cast<float4*>(&tile[b][rr][0])   = make_float4(0.f, 0.f, 0.f, 0.f);
        *reinterpret_cast<float4*>(&tile[b][rr][260]) = make_float4(0.f, 0.f, 0.f, 0.f);
    }

    // ---- weights: block-uniform loads (scalar-load friendly)
    float w[KSIZE * KSIZE];
    const float* wp = gw + c * (KSIZE * KSIZE);
    #pragma unroll
    for (int k = 0; k < KSIZE * KSIZE; ++k) w[k] = wp[k];

    // ---- stage one tile: wave wv handles rows wv, wv+4, ... (38 rows total).
    // Interior 256 cols via global_load_lds (dest = uniform base + lane*16B);
    // out-of-image rows get ds_write zeros.
#define STAGE(BUF, T) do {                                                   \
        const int row0_ = (T) * TH - 3;                                      \
        for (int rr = wv; rr < ROWS; rr += 4) {                              \
            int gr = row0_ + rr;                                             \
            if (gr >= 0 && gr < HW) {                                        \
                gload_lds16(xp + (size_t)gr * HW + lane * 4,                 \
                            &tile[BUF][rr][4]);                              \
            } else {                                                         \
                *reinterpret_cast<float4*>(&tile[BUF][rr][4 + lane * 4]) =   \
                    make_float4(0.f, 0.f, 0.f, 0.f);                         \
            }                                                                \
        }                                                                    \
    } while (0)

    // prologue: stage tile 0 into buffer 0
    STAGE(0, 0);
    __syncthreads();

    const int colp = lane * 4;    // padded col base (16B aligned)
    const int ob   = wv * 8;      // this wave's first tile-row

    for (int t = 0; t < NT; ++t) {
        const int cur = t & 1;

        // issue next tile's prefetch FIRST (in flight across the compute)
        if (t + 1 < NT) STAGE(cur ^ 1, t + 1);

        // ---- compute 8 rows x 4 cols per thread from tile[cur]
        float acc[8][4];
        #pragma unroll
        for (int o = 0; o < 8; ++o)
            #pragma unroll
            for (int cc = 0; cc < 4; ++cc) acc[o][cc] = 0.f;

        #pragma unroll
        for (int r = 0; r < 14; ++r) {      // LDS rows ob..ob+13
            float4 a = *reinterpret_cast<const float4*>(&tile[cur][ob + r][colp]);
            float4 b = *reinterpret_cast<const float4*>(&tile[cur][ob + r][colp + 4]);
            float4 d = *reinterpret_cast<const float4*>(&tile[cur][ob + r][colp + 8]);
            float f[12] = {a.x, a.y, a.z, a.w, b.x, b.y, b.z, b.w, d.x, d.y, d.z, d.w};
            #pragma unroll
            for (int o = 0; o < 8; ++o) {
                if (o <= r && r <= o + 6) {     // compile-time after unroll
                    const int ki = r - o;        // kernel row index 0..6
                    #pragma unroll
                    for (int cc = 0; cc < 4; ++cc) {
                        #pragma unroll
                        for (int j = 0; j < KSIZE; ++j)
                            acc[o][cc] += f[cc + j + 1] * w[ki * KSIZE + j];
                    }
                }
            }
        }

        // ---- store 8 rows x float4, fully coalesced
        const int orow0 = t * TH + ob;
        #pragma unroll
        for (int o = 0; o < 8; ++o) {
            float4 v = make_float4(acc[o][0], acc[o][1], acc[o][2], acc[o][3]);
            *reinterpret_cast<float4*>(op + (size_t)(orow0 + o) * HW + colp) = v;
        }

        // barrier: drains prefetch vmcnt (next tile ready) + LDS r/w ordering
        __syncthreads();
    }
#undef STAGE
}

extern "C" void kernel_launch(void* const* d_in, const int* in_sizes, int n_in,
                              void* d_out, int out_size, void* d_ws, size_t ws_size,
                              hipStream_t stream) {
    const float* x  = (const float*)d_in[0];
    const float* ls = (const float*)d_in[1];
    const float* lf = (const float*)d_in[2];
    const float* th = (const float*)d_in[3];
    float* out = (float*)d_out;
    float* gw  = (float*)d_ws;   // 256*49*4 = 50176 bytes of scratch

    gabor_weights_kernel<<<1, 256, 0, stream>>>(ls, lf, th, gw);

    dim3 grid(C_CH, BATCH);      // one persistent block per (n,c) plane
    gabor_conv_kernel<<<grid, 256, 0, stream>>>(x, gw, out);
}

// Round 3
// 281.093 us; speedup vs baseline: 1.0530x; 1.0033x over previous
//
#include <hip/hip_runtime.h>
#include <math.h>

#define KSIZE 7
#define C_CH  256
#define HW    256
#define BATCH 8

#define TH    32            // output rows per tile
#define ROWS  (TH + 6)      // 38 input rows staged (3-row halo each side)
#define LDW   264           // 4 zero + 256 + 4 zero padded floats per LDS row
#define NT    (HW / TH)     // 8 tiles per (n,c) plane

// ---------------------------------------------------------------------------
// Kernel 1: synthesize the 256 x 7 x 7 Gabor filter bank into d_ws.
// ---------------------------------------------------------------------------
__global__ void gabor_weights_kernel(const float* __restrict__ log_sigma,
                                     const float* __restrict__ log_freq,
                                     const float* __restrict__ theta,
                                     float* __restrict__ gw) {
    int c = threadIdx.x;
    if (c >= C_CH) return;
    float sigma = expf(log_sigma[c]);
    float freq  = expf(log_freq[c]);
    float ct = cosf(theta[c]);
    float st = sinf(theta[c]);
    float inv_sigma = 1.0f / sigma;
    float vals[KSIZE * KSIZE];
    float sum = 0.0f;
    #pragma unroll
    for (int i = 0; i < KSIZE; ++i) {
        #pragma unroll
        for (int j = 0; j < KSIZE; ++j) {
            float dx = (float)(i - 3);
            float dy = (float)(j - 3);
            float x0 = (dx * ct + dy * st) * inv_sigma;
            float x1 = (-dx * st + dy * ct) * inv_sigma;
            float g  = expf(-0.5f * (x0 * x0 + x1 * x1));
            float v  = g * cosf(6.283185307179586f * freq * x0);
            vals[i * KSIZE + j] = v;
            sum += v;
        }
    }
    float inv = 1.0f / sum;
    #pragma unroll
    for (int k = 0; k < KSIZE * KSIZE; ++k)
        gw[c * (KSIZE * KSIZE) + k] = vals[k] * inv;
}

// ---------------------------------------------------------------------------
// Kernel 2: depthwise 7x7 conv; persistent block per (n,c) plane; streaming
// row-tiles, double-buffered LDS, global_load_lds prefetch with COUNTED
// vmcnt (stores never on critical path), halo rows reused LDS->LDS.
// Per tile: stage(next) [halo ds-copy + 7-8 gloads/wave] -> compute ->
// 8 stores -> s_waitcnt vmcnt(8) lgkmcnt(0) -> s_barrier.
// vmcnt(8): the 8 newest outstanding vmem ops are this tile's stores
// (issued after the loads; in-order retirement) => loads drained, stores not.
// ---------------------------------------------------------------------------
__device__ __forceinline__ void gload_lds16(const float* g, float* l) {
    __builtin_amdgcn_global_load_lds(
        (const __attribute__((address_space(1))) void*)g,
        (__attribute__((address_space(3))) void*)l,
        16, 0, 0);
}

__global__ __launch_bounds__(256, 2)
void gabor_conv_kernel(const float* __restrict__ x,
                       const float* __restrict__ gw,
                       float* __restrict__ out) {
    __shared__ float tile[2][ROWS][LDW];

    const int tid  = threadIdx.x;
    const int lane = tid & 63;    // column quad: output cols 4*lane..4*lane+3
    const int wv   = tid >> 6;    // wave id: output rows 8*wv..8*wv+7
    const int c    = blockIdx.x;
    const int n    = blockIdx.y;

    const size_t plane = ((size_t)n * C_CH + c) * (size_t)(HW * HW);
    const float* xp = x + plane;
    float*       op = out + plane;

    // ---- zero the pad columns of BOTH buffers once
    for (int idx = tid; idx < 2 * ROWS; idx += 256) {
        int b  = idx / ROWS;
        int rr = idx - b * ROWS;
        *reinterpret_cast<float4*>(&tile[b][rr][0])   = make_float4(0.f, 0.f, 0.f, 0.f);
        *reinterpret_cast<float4*>(&tile[b][rr][260]) = make_float4(0.f, 0.f, 0.f, 0.f);
    }

    // ---- weights (block-uniform)
    float w[KSIZE * KSIZE];
    const float* wp = gw + c * (KSIZE * KSIZE);
    #pragma unroll
    for (int k = 0; k < KSIZE * KSIZE; ++k) w[k] = wp[k];

    // ---- prologue: stage tile 0 into buf 0 (rows 0..2 zero, rows 3..37 load)
    for (int i = tid; i < 3 * 64; i += 256) {
        int r = i >> 6, q = i & 63;
        *reinterpret_cast<float4*>(&tile[0][r][4 + q * 4]) = make_float4(0.f, 0.f, 0.f, 0.f);
    }
    for (int rr = 3 + wv; rr < ROWS; rr += 4)
        gload_lds16(xp + (size_t)(rr - 3) * HW + lane * 4, &tile[0][rr][4]);
    asm volatile("s_waitcnt vmcnt(0) lgkmcnt(0)" ::: "memory");
    __builtin_amdgcn_s_barrier();

    const int colp = lane * 4;    // padded col base (16B aligned)
    const int ob   = wv * 8;      // this wave's first tile-row

    for (int t = 0; t < NT; ++t) {
        const int cur = t & 1;
        const int nxt = cur ^ 1;

        // ---- stage next tile FIRST (loads in flight across the compute)
        if (t + 1 < NT) {
            // halo: rows 0..5 of nxt = rows 32..37 of cur (LDS->LDS, no HBM)
            for (int i = tid; i < 6 * 64; i += 256) {
                int r = i >> 6, q = i & 63;
                *reinterpret_cast<float4*>(&tile[nxt][r][4 + q * 4]) =
                    *reinterpret_cast<const float4*>(&tile[cur][32 + r][4 + q * 4]);
            }
            // bottom-of-image zeros for the last tile
            if (t + 1 == NT - 1) {
                for (int i = tid; i < 3 * 64; i += 256) {
                    int r = 35 + (i >> 6), q = i & 63;
                    *reinterpret_cast<float4*>(&tile[nxt][r][4 + q * 4]) =
                        make_float4(0.f, 0.f, 0.f, 0.f);
                }
            }
            // fresh rows 6..37 (6..34 for last tile): 7-8 gloads per wave
            const int row0 = (t + 1) * TH - 3;
            const int rmax = (t + 1 == NT - 1) ? 34 : 37;
            for (int rr = 6 + wv; rr <= rmax; rr += 4)
                gload_lds16(xp + (size_t)(row0 + rr) * HW + lane * 4,
                            &tile[nxt][rr][4]);
        }
        // pin issue order: all loads above stay above the stores below
        asm volatile("" ::: "memory");

        // ---- compute 8 rows x 4 cols per thread from tile[cur]
        float acc[8][4];
        #pragma unroll
        for (int o = 0; o < 8; ++o)
            #pragma unroll
            for (int cc = 0; cc < 4; ++cc) acc[o][cc] = 0.f;

        #pragma unroll
        for (int r = 0; r < 14; ++r) {      // LDS rows ob..ob+13
            float4 a = *reinterpret_cast<const float4*>(&tile[cur][ob + r][colp]);
            float4 b = *reinterpret_cast<const float4*>(&tile[cur][ob + r][colp + 4]);
            float4 d = *reinterpret_cast<const float4*>(&tile[cur][ob + r][colp + 8]);
            float f[12] = {a.x, a.y, a.z, a.w, b.x, b.y, b.z, b.w, d.x, d.y, d.z, d.w};
            #pragma unroll
            for (int o = 0; o < 8; ++o) {
                if (o <= r && r <= o + 6) {     // compile-time after unroll
                    const int ki = r - o;        // kernel row index 0..6
                    #pragma unroll
                    for (int cc = 0; cc < 4; ++cc) {
                        #pragma unroll
                        for (int j = 0; j < KSIZE; ++j)
                            acc[o][cc] += f[cc + j + 1] * w[ki * KSIZE + j];
                    }
                }
            }
        }

        // ---- store 8 rows x float4 (issued AFTER the prefetch loads)
        const int orow0 = t * TH + ob;
        #pragma unroll
        for (int o = 0; o < 8; ++o) {
            float4 v = make_float4(acc[o][0], acc[o][1], acc[o][2], acc[o][3]);
            *reinterpret_cast<float4*>(op + (size_t)(orow0 + o) * HW + colp) = v;
        }

        // ---- counted wait: drain loads (oldest), NOT this tile's 8 stores
        if (t + 1 < NT) {
            asm volatile("s_waitcnt vmcnt(8) lgkmcnt(0)" ::: "memory");
            __builtin_amdgcn_s_barrier();
        }
        // last tile: stores flushed at kernel end
    }
}

extern "C" void kernel_launch(void* const* d_in, const int* in_sizes, int n_in,
                              void* d_out, int out_size, void* d_ws, size_t ws_size,
                              hipStream_t stream) {
    const float* x  = (const float*)d_in[0];
    const float* ls = (const float*)d_in[1];
    const float* lf = (const float*)d_in[2];
    const float* th = (const float*)d_in[3];
    float* out = (float*)d_out;
    float* gw  = (float*)d_ws;   // 256*49*4 = 50176 bytes of scratch

    gabor_weights_kernel<<<1, 256, 0, stream>>>(ls, lf, th, gw);

    dim3 grid(C_CH, BATCH);      // one persistent block per (n,c) plane
    gabor_conv_kernel<<<grid, 256, 0, stream>>>(x, gw, out);
}